// Round 12
// baseline (343.714 us; speedup 1.0000x reference)
//
#include <hip/hip_runtime.h>

#define N_NODES 100000
#define HID 64
#define N_EDGES 1600000
#define NB 391                 // ceil(N_NODES / 256) buckets of 256 nodes
#define C_EPB 6400             // edges per block in bucket_scatter (250 blocks)
#define G_GATHER 6250          // N_NODES*16/256 gather blocks (exact)
#define NT 6250                // 16-row MFMA tiles
#define FUSE_BLOCKS ((NT + 3) / 4)   // 1563 blocks x 4 waves = 6252 waves

typedef __attribute__((ext_vector_type(8))) short bf16x8;
typedef __attribute__((ext_vector_type(4))) float f32x4;

// ---- bf16 helpers (manual, RNE) ------------------------------------------
__device__ __forceinline__ unsigned short f2bf(float f) {
    unsigned u = __float_as_uint(f);
    u = (u + 0x7FFFu + ((u >> 16) & 1u)) >> 16;
    return (unsigned short)u;
}
__device__ __forceinline__ float bflo(unsigned w) { return __uint_as_float(w << 16); }
__device__ __forceinline__ float bfhi(unsigned w) { return __uint_as_float(w & 0xFFFF0000u); }

// ---------------------------------------------------------------- gather + hist
__global__ void gather_hist_kernel(const float* __restrict__ emb,
                                   const int* __restrict__ nid,
                                   unsigned short* __restrict__ xh,
                                   const int* __restrict__ dst,
                                   int* __restrict__ bhist) {
    __shared__ int h[NB];
    if (blockIdx.x < G_GATHER) {
        int i = blockIdx.x * blockDim.x + threadIdx.x;   // < 1.6M exactly
        int row = i >> 4;
        int c   = i & 15;
        int s   = nid[row];
        float4 v = reinterpret_cast<const float4*>(emb)[(size_t)s * 16 + c];
        uint2 p;
        p.x = (unsigned)f2bf(v.x) | ((unsigned)f2bf(v.y) << 16);
        p.y = (unsigned)f2bf(v.z) | ((unsigned)f2bf(v.w) << 16);
        reinterpret_cast<uint2*>(xh)[(size_t)row * 16 + c] = p;
    } else {
        int hb = blockIdx.x - G_GATHER;
        for (int i = threadIdx.x; i < NB; i += blockDim.x) h[i] = 0;
        __syncthreads();
        int nt = 256 * blockDim.x;
        const int4* d4 = (const int4*)dst;
        for (int q = hb * blockDim.x + threadIdx.x; q < N_EDGES / 4; q += nt) {
            int4 v = d4[q];
            atomicAdd(&h[v.x >> 8], 1);
            atomicAdd(&h[v.y >> 8], 1);
            atomicAdd(&h[v.z >> 8], 1);
            atomicAdd(&h[v.w >> 8], 1);
        }
        __syncthreads();
        for (int i = threadIdx.x; i < NB; i += blockDim.x)
            if (h[i]) atomicAdd(&bhist[i], h[i]);
    }
}

// ---------------------------------------------------------------- CSR build, pass B
__global__ void bucket_scan(const int* __restrict__ bhist,
                            int* __restrict__ boff,
                            int* __restrict__ bcursor) {
    __shared__ int s[512];
    int v = (threadIdx.x < NB) ? bhist[threadIdx.x] : 0;
    s[threadIdx.x] = v;
    __syncthreads();
    for (int off = 1; off < 512; off <<= 1) {
        int t = (threadIdx.x >= off) ? s[threadIdx.x - off] : 0;
        __syncthreads();
        s[threadIdx.x] += t;
        __syncthreads();
    }
    if (threadIdx.x < NB) {
        int ex = s[threadIdx.x] - v;
        boff[threadIdx.x] = ex;
        bcursor[threadIdx.x] = ex;
    }
}

// ---------------------------------------------------------------- CSR build, pass C
__global__ void bucket_scatter(const int* __restrict__ src,
                               const int* __restrict__ dst,
                               int* __restrict__ bcursor,
                               int2* __restrict__ pairs) {
    __shared__ int h[NB];
    __shared__ int base[NB];
    for (int i = threadIdx.x; i < NB; i += blockDim.x) h[i] = 0;
    __syncthreads();
    int q0 = blockIdx.x * (C_EPB / 4);
    int q1 = q0 + (C_EPB / 4);
    const int4* d4 = (const int4*)dst;
    const int4* s4 = (const int4*)src;
    for (int q = q0 + threadIdx.x; q < q1; q += blockDim.x) {
        int4 v = d4[q];
        atomicAdd(&h[v.x >> 8], 1);
        atomicAdd(&h[v.y >> 8], 1);
        atomicAdd(&h[v.z >> 8], 1);
        atomicAdd(&h[v.w >> 8], 1);
    }
    __syncthreads();
    for (int i = threadIdx.x; i < NB; i += blockDim.x) {
        int c = h[i];
        base[i] = c ? atomicAdd(&bcursor[i], c) : 0;
    }
    __syncthreads();
    for (int i = threadIdx.x; i < NB; i += blockDim.x) h[i] = 0;
    __syncthreads();
    for (int q = q0 + threadIdx.x; q < q1; q += blockDim.x) {
        int4 d = d4[q];
        int4 s = s4[q];
        int b, slot;
        b = d.x >> 8; slot = base[b] + atomicAdd(&h[b], 1); pairs[slot] = make_int2(s.x, d.x);
        b = d.y >> 8; slot = base[b] + atomicAdd(&h[b], 1); pairs[slot] = make_int2(s.y, d.y);
        b = d.z >> 8; slot = base[b] + atomicAdd(&h[b], 1); pairs[slot] = make_int2(s.z, d.z);
        b = d.w >> 8; slot = base[b] + atomicAdd(&h[b], 1); pairs[slot] = make_int2(s.w, d.w);
    }
}

// ---------------------------------------------------------------- CSR build, pass D
__global__ void bucket_csr(const int2* __restrict__ pairs,
                           const int* __restrict__ boff,
                           const int* __restrict__ bcursor,
                           int* __restrict__ row_start,
                           int* __restrict__ adj) {
    __shared__ int cnt[256];
    __shared__ int sc[256];
    int b = blockIdx.x;
    int node0 = b << 8;
    int p0 = boff[b];
    int p1 = bcursor[b];           // after pass C, bcursor[b] = end of bucket b
    int t = threadIdx.x;
    cnt[t] = 0;
    __syncthreads();
    for (int p = p0 + t; p < p1; p += 256)
        atomicAdd(&cnt[pairs[p].y & 255], 1);
    __syncthreads();
    int v = cnt[t];
    sc[t] = v;
    __syncthreads();
    for (int off = 1; off < 256; off <<= 1) {
        int u = (t >= off) ? sc[t - off] : 0;
        __syncthreads();
        sc[t] += u;
        __syncthreads();
    }
    sc[t] = p0 + sc[t] - v;        // exclusive scan + bucket base = row_start
    __syncthreads();
    int node = node0 + t;
    if (node <= N_NODES) row_start[node] = sc[t];
    __syncthreads();               // row_start read before atomics mutate sc
    for (int p = p0 + t; p < p1; p += 256) {
        int2 pr = pairs[p];
        int slot = atomicAdd(&sc[pr.y & 255], 1);
        adj[slot] = pr.x;
    }
}

// ---------------------------------------------------------------- fused SAGE layer v2
// One wave per 16-row tile, rows processed WAVE-UNIFORMLY (agg_kernel's proven
// 4-slot x 16-lane uint2 gather, no degree divergence). Mean rows staged into
// LDS in MFMA A-fragment order; weights staged once per block in B-frag order.
// Aggregation output never touches global memory.
//   A-frag elem (row m, feature f) at sA short offset (f>>3)*128 + m*8 + (f&7)
//   B-frag elem (out n, k)        at sW short offset mat*4096 + (k>>3)*512 + n*8 + (k&7)
// LDS: sW = 8192 shorts = 16 KB (uint4[1024]!  R11 bug: [512] aliased sA), sA = 8 KB.
__global__ void __launch_bounds__(256, 6)
sage_fused2(const int* __restrict__ row_start,
            const int* __restrict__ adj,
            const unsigned short* __restrict__ xh,
            const float* __restrict__ Wl,
            const float* __restrict__ Wr,
            const float* __restrict__ bias,
            unsigned short* __restrict__ H,
            int relu) {
    __shared__ uint4 sWq[1024];       // 8192 bf16 = 16 KB (both matrices)
    __shared__ uint4 sAq[4 * 128];    // 4 waves x 1024 bf16 = 8 KB
    unsigned short* sW = (unsigned short*)sWq;

    // ---- stage weights into B-frag order (once per block)
    for (int i = threadIdx.x; i < 8192; i += 256) {
        int mat = i >> 12;
        int nn  = (i >> 6) & 63;
        int k   = i & 63;
        const float* W = mat ? Wr : Wl;
        sW[mat * 4096 + (k >> 3) * 512 + nn * 8 + (k & 7)] = f2bf(W[nn * 64 + k]);
    }
    __syncthreads();

    int lane = threadIdx.x & 63;
    int w    = threadIdx.x >> 6;
    unsigned short* sA = (unsigned short*)(sAq + w * 128);

    int tile = blockIdx.x * 4 + w;
    int valid = tile < NT;

    // ---- phase 1: aggregate 16 rows wave-uniformly into LDS (A-frag order)
    if (valid) {
        int slot = lane >> 4;           // 0..3 edge slot
        int c    = lane & 15;           // uint2 feature column (features 4c..4c+3)
        const uint2* xw = (const uint2*)xh;
        for (int r = 0; r < 16; ++r) {
            int row = tile * 16 + r;
            int beg = row_start[row], end = row_start[row + 1];
            float a0 = 0.f, a1 = 0.f, a2 = 0.f, a3 = 0.f;
            int j = beg + slot;
            for (; j + 12 < end; j += 16) {   // 16 uint2 gathers in flight/wave
                int s0 = adj[j], s1 = adj[j + 4], s2 = adj[j + 8], s3 = adj[j + 12];
                uint2 v0 = xw[(size_t)s0 * 16 + c];
                uint2 v1 = xw[(size_t)s1 * 16 + c];
                uint2 v2 = xw[(size_t)s2 * 16 + c];
                uint2 v3 = xw[(size_t)s3 * 16 + c];
                a0 += bflo(v0.x) + bflo(v1.x) + bflo(v2.x) + bflo(v3.x);
                a1 += bfhi(v0.x) + bfhi(v1.x) + bfhi(v2.x) + bfhi(v3.x);
                a2 += bflo(v0.y) + bflo(v1.y) + bflo(v2.y) + bflo(v3.y);
                a3 += bfhi(v0.y) + bfhi(v1.y) + bfhi(v2.y) + bfhi(v3.y);
            }
            for (; j < end; j += 4) {
                uint2 v = xw[(size_t)adj[j] * 16 + c];
                a0 += bflo(v.x); a1 += bfhi(v.x);
                a2 += bflo(v.y); a3 += bfhi(v.y);
            }
            a0 += __shfl_xor(a0, 16); a0 += __shfl_xor(a0, 32);
            a1 += __shfl_xor(a1, 16); a1 += __shfl_xor(a1, 32);
            a2 += __shfl_xor(a2, 16); a2 += __shfl_xor(a2, 32);
            a3 += __shfl_xor(a3, 16); a3 += __shfl_xor(a3, 32);
            if (slot == 0) {
                float inv = 1.0f / fmaxf((float)(end - beg), 1.0f);
                uint2 p;
                p.x = (unsigned)f2bf(a0 * inv) | ((unsigned)f2bf(a1 * inv) << 16);
                p.y = (unsigned)f2bf(a2 * inv) | ((unsigned)f2bf(a3 * inv) << 16);
                // features 4c..4c+3 of row r, A-frag order; 8B-aligned
                *(uint2*)(sA + (c >> 1) * 128 + r * 8 + 4 * (c & 1)) = p;
            }
        }
    }
    __syncthreads();

    // ---- phase 2: MFMA from LDS frags + global self rows
    if (valid) {
        int m = lane & 15, quad = lane >> 4;
        bf16x8 am0 = *(const bf16x8*)(sA + (0 * 4 + quad) * 128 + m * 8);  // ks=0
        bf16x8 am1 = *(const bf16x8*)(sA + (1 * 4 + quad) * 128 + m * 8);  // ks=1
        size_t rowbase = ((size_t)tile * 16 + m) * HID;
        bf16x8 as0 = *(const bf16x8*)(xh + rowbase + quad * 8);
        bf16x8 as1 = *(const bf16x8*)(xh + rowbase + 32 + quad * 8);

        f32x4 acc[4] = {{0,0,0,0},{0,0,0,0},{0,0,0,0},{0,0,0,0}};
        #pragma unroll
        for (int ct = 0; ct < 4; ++ct) {
            int n = ct * 16 + m;
            bf16x8 bl0 = *(const bf16x8*)(sW + (0 * 4 + quad) * 512 + n * 8);
            bf16x8 bl1 = *(const bf16x8*)(sW + (1 * 4 + quad) * 512 + n * 8);
            bf16x8 br0 = *(const bf16x8*)(sW + 4096 + (0 * 4 + quad) * 512 + n * 8);
            bf16x8 br1 = *(const bf16x8*)(sW + 4096 + (1 * 4 + quad) * 512 + n * 8);
            acc[ct] = __builtin_amdgcn_mfma_f32_16x16x32_bf16(am0, bl0, acc[ct], 0, 0, 0);
            acc[ct] = __builtin_amdgcn_mfma_f32_16x16x32_bf16(am1, bl1, acc[ct], 0, 0, 0);
            acc[ct] = __builtin_amdgcn_mfma_f32_16x16x32_bf16(as0, br0, acc[ct], 0, 0, 0);
            acc[ct] = __builtin_amdgcn_mfma_f32_16x16x32_bf16(as1, br1, acc[ct], 0, 0, 0);
        }
        #pragma unroll
        for (int ct = 0; ct < 4; ++ct) {
            float bv = bias[ct * 16 + m];
            #pragma unroll
            for (int r = 0; r < 4; ++r) {
                float v = acc[ct][r] + bv;
                if (relu) v = fmaxf(v, 0.f);
                H[((size_t)tile * 16 + quad * 4 + r) * HID + ct * 16 + m] = f2bf(v);
            }
        }
    }
}

// ---------------------------------------------------------------- edge dot (bf16)
__global__ void edge_dot_kernel(const int* __restrict__ src,
                                const int* __restrict__ dst,
                                const unsigned short* __restrict__ h,
                                float* __restrict__ out) {
    int t = blockIdx.x * blockDim.x + threadIdx.x;
    int g = t >> 3;                 // edge-pair group
    int c = t & 7;
    int e0 = g * 2;
    if (e0 >= N_EDGES) return;
    int a0 = src[e0],     b0 = dst[e0];
    int a1 = src[e0 + 1], b1 = dst[e0 + 1];
    const uint4* h4 = reinterpret_cast<const uint4*>(h);
    uint4 va0 = h4[(size_t)a0 * 8 + c];
    uint4 vb0 = h4[(size_t)b0 * 8 + c];
    uint4 va1 = h4[(size_t)a1 * 8 + c];
    uint4 vb1 = h4[(size_t)b1 * 8 + c];
    float p0 = bflo(va0.x) * bflo(vb0.x) + bfhi(va0.x) * bfhi(vb0.x)
             + bflo(va0.y) * bflo(vb0.y) + bfhi(va0.y) * bfhi(vb0.y)
             + bflo(va0.z) * bflo(vb0.z) + bfhi(va0.z) * bfhi(vb0.z)
             + bflo(va0.w) * bflo(vb0.w) + bfhi(va0.w) * bfhi(vb0.w);
    float p1 = bflo(va1.x) * bflo(vb1.x) + bfhi(va1.x) * bfhi(vb1.x)
             + bflo(va1.y) * bflo(vb1.y) + bfhi(va1.y) * bfhi(vb1.y)
             + bflo(va1.z) * bflo(vb1.z) + bfhi(va1.z) * bfhi(vb1.z)
             + bflo(va1.w) * bflo(vb1.w) + bfhi(va1.w) * bfhi(vb1.w);
    p0 += __shfl_xor(p0, 1); p0 += __shfl_xor(p0, 2); p0 += __shfl_xor(p0, 4);
    p1 += __shfl_xor(p1, 1); p1 += __shfl_xor(p1, 2); p1 += __shfl_xor(p1, 4);
    if (c == 0) reinterpret_cast<float2*>(out)[g] = make_float2(p0, p1);
}

extern "C" void kernel_launch(void* const* d_in, const int* in_sizes, int n_in,
                              void* d_out, int out_size, void* d_ws, size_t ws_size,
                              hipStream_t stream) {
    const float* emb = (const float*)d_in[0];
    const float* Wl1 = (const float*)d_in[1];
    const float* Wr1 = (const float*)d_in[2];
    const float* b1  = (const float*)d_in[3];
    const float* Wl2 = (const float*)d_in[4];
    const float* Wr2 = (const float*)d_in[5];
    const float* b2  = (const float*)d_in[6];
    const int*   nid = (const int*)d_in[7];
    const int*   ei  = (const int*)d_in[8];
    const int* esrc = ei;
    const int* edst = ei + N_EDGES;
    float* out = (float*)d_out;

    const size_t NH = (size_t)N_NODES * HID;   // 6.4M elements
    unsigned short* xh  = (unsigned short*)d_ws;          // [N,64] bf16
    unsigned short* h1h = xh + NH;                        // [N,64] bf16
    unsigned short* h2h = h1h + NH;                       // [N,64] bf16
    int* ib        = (int*)(h2h + NH);                    // int region
    int* row_start = ib;                          // [N+1]
    int* adj       = ib + N_NODES + 64;           // [E]
    int2* pairs    = (int2*)(adj + N_EDGES + 64); // [E] (src,dst)
    int* bhist     = (int*)(pairs + N_EDGES);     // [NB]
    int* boff      = bhist + NB + 1;              // [NB]
    int* bcursor   = boff + NB + 1;               // [NB]

    hipMemsetAsync(bhist, 0, NB * sizeof(int), stream);

    // xh = bf16(emb[node_id])  +  bucket histogram (role-split grid)
    gather_hist_kernel<<<G_GATHER + 256, 256, 0, stream>>>(emb, nid, xh, edst, bhist);

    // ---- CSR build via bucket counting sort (shared by both layers)
    bucket_scan<<<1, 512, 0, stream>>>(bhist, boff, bcursor);
    bucket_scatter<<<N_EDGES / C_EPB, 256, 0, stream>>>(esrc, edst, bcursor, pairs);
    bucket_csr<<<NB, 256, 0, stream>>>(pairs, boff, bcursor, row_start, adj);

    // ---- fused layers: wave-uniform aggregate -> LDS transpose -> MFMA
    sage_fused2<<<FUSE_BLOCKS, 256, 0, stream>>>(row_start, adj, xh,  Wl1, Wr1, b1, h1h, 1);
    sage_fused2<<<FUSE_BLOCKS, 256, 0, stream>>>(row_start, adj, h1h, Wl2, Wr2, b2, h2h, 0);

    // ---- edge classifier on bf16 features
    edge_dot_kernel<<<((size_t)(N_EDGES / 2) * 8 + 255) / 256, 256, 0, stream>>>(esrc, edst, h2h, out);
}

// Round 13
// 304.976 us; speedup vs baseline: 1.1270x; 1.1270x over previous
//
#include <hip/hip_runtime.h>

#define N_NODES 100000
#define HID 64
#define N_EDGES 1600000
#define NB 391                 // ceil(N_NODES / 256) buckets of 256 nodes
#define C_EPB 6400             // edges per block in bucket_scatter (250 blocks)
#define G_GATHER 6250          // N_NODES*16/256 gather blocks (exact)

typedef __attribute__((ext_vector_type(8))) short bf16x8;
typedef __attribute__((ext_vector_type(4))) float f32x4;

// ---- bf16 helpers (manual, RNE) ------------------------------------------
__device__ __forceinline__ unsigned short f2bf(float f) {
    unsigned u = __float_as_uint(f);
    u = (u + 0x7FFFu + ((u >> 16) & 1u)) >> 16;
    return (unsigned short)u;
}
__device__ __forceinline__ float bflo(unsigned w) { return __uint_as_float(w << 16); }
__device__ __forceinline__ float bfhi(unsigned w) { return __uint_as_float(w & 0xFFFF0000u); }

// ---------------------------------------------------------------- gather + hist
// Role-split grid: blocks [0,G_GATHER) do xh = bf16(emb[node_id]);
// blocks [G_GATHER, G_GATHER+256) do the global bucket histogram (dst>>8).
__global__ void gather_hist_kernel(const float* __restrict__ emb,
                                   const int* __restrict__ nid,
                                   unsigned short* __restrict__ xh,
                                   const int* __restrict__ dst,
                                   int* __restrict__ bhist) {
    __shared__ int h[NB];
    if (blockIdx.x < G_GATHER) {
        int i = blockIdx.x * blockDim.x + threadIdx.x;   // < 1.6M exactly
        int row = i >> 4;
        int c   = i & 15;
        int s   = nid[row];
        float4 v = reinterpret_cast<const float4*>(emb)[(size_t)s * 16 + c];
        uint2 p;
        p.x = (unsigned)f2bf(v.x) | ((unsigned)f2bf(v.y) << 16);
        p.y = (unsigned)f2bf(v.z) | ((unsigned)f2bf(v.w) << 16);
        reinterpret_cast<uint2*>(xh)[(size_t)row * 16 + c] = p;
    } else {
        int hb = blockIdx.x - G_GATHER;
        for (int i = threadIdx.x; i < NB; i += blockDim.x) h[i] = 0;
        __syncthreads();
        int nt = 256 * blockDim.x;
        const int4* d4 = (const int4*)dst;
        for (int q = hb * blockDim.x + threadIdx.x; q < N_EDGES / 4; q += nt) {
            int4 v = d4[q];
            atomicAdd(&h[v.x >> 8], 1);
            atomicAdd(&h[v.y >> 8], 1);
            atomicAdd(&h[v.z >> 8], 1);
            atomicAdd(&h[v.w >> 8], 1);
        }
        __syncthreads();
        for (int i = threadIdx.x; i < NB; i += blockDim.x)
            if (h[i]) atomicAdd(&bhist[i], h[i]);
    }
}

// ---------------------------------------------------------------- CSR build, pass B
__global__ void bucket_scan(const int* __restrict__ bhist,
                            int* __restrict__ boff,
                            int* __restrict__ bcursor) {
    __shared__ int s[512];
    int v = (threadIdx.x < NB) ? bhist[threadIdx.x] : 0;
    s[threadIdx.x] = v;
    __syncthreads();
    for (int off = 1; off < 512; off <<= 1) {
        int t = (threadIdx.x >= off) ? s[threadIdx.x - off] : 0;
        __syncthreads();
        s[threadIdx.x] += t;
        __syncthreads();
    }
    if (threadIdx.x < NB) {
        int ex = s[threadIdx.x] - v;
        boff[threadIdx.x] = ex;
        bcursor[threadIdx.x] = ex;
    }
}

// ---------------------------------------------------------------- CSR build, pass C
// Packed pairs: (src << 8) | (dst & 255)  -- src < 2^17 so this fits in 25 bits.
// Halves the scattered write vs int2 pairs.
__global__ void bucket_scatter(const int* __restrict__ src,
                               const int* __restrict__ dst,
                               int* __restrict__ bcursor,
                               int* __restrict__ pairs) {
    __shared__ int h[NB];
    __shared__ int base[NB];
    for (int i = threadIdx.x; i < NB; i += blockDim.x) h[i] = 0;
    __syncthreads();
    int q0 = blockIdx.x * (C_EPB / 4);
    int q1 = q0 + (C_EPB / 4);
    const int4* d4 = (const int4*)dst;
    const int4* s4 = (const int4*)src;
    for (int q = q0 + threadIdx.x; q < q1; q += blockDim.x) {
        int4 v = d4[q];
        atomicAdd(&h[v.x >> 8], 1);
        atomicAdd(&h[v.y >> 8], 1);
        atomicAdd(&h[v.z >> 8], 1);
        atomicAdd(&h[v.w >> 8], 1);
    }
    __syncthreads();
    for (int i = threadIdx.x; i < NB; i += blockDim.x) {
        int c = h[i];
        base[i] = c ? atomicAdd(&bcursor[i], c) : 0;
    }
    __syncthreads();
    for (int i = threadIdx.x; i < NB; i += blockDim.x) h[i] = 0;
    __syncthreads();
    for (int q = q0 + threadIdx.x; q < q1; q += blockDim.x) {
        int4 d = d4[q];
        int4 s = s4[q];
        int b, slot;
        b = d.x >> 8; slot = base[b] + atomicAdd(&h[b], 1); pairs[slot] = (s.x << 8) | (d.x & 255);
        b = d.y >> 8; slot = base[b] + atomicAdd(&h[b], 1); pairs[slot] = (s.y << 8) | (d.y & 255);
        b = d.z >> 8; slot = base[b] + atomicAdd(&h[b], 1); pairs[slot] = (s.z << 8) | (d.z & 255);
        b = d.w >> 8; slot = base[b] + atomicAdd(&h[b], 1); pairs[slot] = (s.w << 8) | (d.w & 255);
    }
}

// ---------------------------------------------------------------- CSR build, pass D
__global__ void bucket_csr(const int* __restrict__ pairs,
                           const int* __restrict__ boff,
                           const int* __restrict__ bcursor,
                           int* __restrict__ row_start,
                           int* __restrict__ adj) {
    __shared__ int cnt[256];
    __shared__ int sc[256];
    int b = blockIdx.x;
    int node0 = b << 8;
    int p0 = boff[b];
    int p1 = bcursor[b];           // after pass C, bcursor[b] = end of bucket b
    int t = threadIdx.x;
    cnt[t] = 0;
    __syncthreads();
    for (int p = p0 + t; p < p1; p += 256)
        atomicAdd(&cnt[pairs[p] & 255], 1);
    __syncthreads();
    int v = cnt[t];
    sc[t] = v;
    __syncthreads();
    for (int off = 1; off < 256; off <<= 1) {
        int u = (t >= off) ? sc[t - off] : 0;
        __syncthreads();
        sc[t] += u;
        __syncthreads();
    }
    sc[t] = p0 + sc[t] - v;        // exclusive scan + bucket base = row_start
    __syncthreads();
    int node = node0 + t;
    if (node <= N_NODES) row_start[node] = sc[t];
    __syncthreads();               // row_start read before atomics mutate sc
    for (int p = p0 + t; p < p1; p += 256) {
        int pr = pairs[p];
        int slot = atomicAdd(&sc[pr & 255], 1);
        adj[slot] = ((unsigned)pr) >> 8;
    }
}

// ---------------------------------------------------------------- aggregation
// Pure gather+mean, NO LDS. 4 edge-slots x 16 lanes, uint2 loads; 16 gathers
// in flight per wave. Grid 2048 (8 blocks/CU) -- proven R9 configuration.
__global__ void agg_kernel(const int* __restrict__ row_start,
                           const int* __restrict__ adj,
                           const unsigned short* __restrict__ xh,
                           unsigned short* __restrict__ M) {
    int lane = threadIdx.x & 63;
    int slot = lane >> 4;               // 0..3  edge slot
    int c    = lane & 15;               // uint2 column (features 4c..4c+3)
    int wpb = blockDim.x >> 6;
    int wid = blockIdx.x * wpb + (threadIdx.x >> 6);
    int stride = gridDim.x * wpb;
    const uint2* xw = (const uint2*)xh;   // row stride = 16 uint2
    uint2* Mw = (uint2*)M;
    for (int row = wid; row < N_NODES; row += stride) {
        int beg = row_start[row], end = row_start[row + 1];
        float a0 = 0.f, a1 = 0.f, a2 = 0.f, a3 = 0.f;
        int j = beg + slot;
        for (; j + 12 < end; j += 16) {   // 4 uint2 gathers in flight per slot
            int s0 = adj[j], s1 = adj[j + 4], s2 = adj[j + 8], s3 = adj[j + 12];
            uint2 v0 = xw[(size_t)s0 * 16 + c];
            uint2 v1 = xw[(size_t)s1 * 16 + c];
            uint2 v2 = xw[(size_t)s2 * 16 + c];
            uint2 v3 = xw[(size_t)s3 * 16 + c];
            a0 += bflo(v0.x) + bflo(v1.x) + bflo(v2.x) + bflo(v3.x);
            a1 += bfhi(v0.x) + bfhi(v1.x) + bfhi(v2.x) + bfhi(v3.x);
            a2 += bflo(v0.y) + bflo(v1.y) + bflo(v2.y) + bflo(v3.y);
            a3 += bfhi(v0.y) + bfhi(v1.y) + bfhi(v2.y) + bfhi(v3.y);
        }
        for (; j < end; j += 4) {
            uint2 v = xw[(size_t)adj[j] * 16 + c];
            a0 += bflo(v.x); a1 += bfhi(v.x);
            a2 += bflo(v.y); a3 += bfhi(v.y);
        }
        a0 += __shfl_xor(a0, 16); a0 += __shfl_xor(a0, 32);
        a1 += __shfl_xor(a1, 16); a1 += __shfl_xor(a1, 32);
        a2 += __shfl_xor(a2, 16); a2 += __shfl_xor(a2, 32);
        a3 += __shfl_xor(a3, 16); a3 += __shfl_xor(a3, 32);
        if (slot == 0) {
            float inv = 1.0f / fmaxf((float)(end - beg), 1.0f);
            uint2 p;
            p.x = (unsigned)f2bf(a0 * inv) | ((unsigned)f2bf(a1 * inv) << 16);
            p.y = (unsigned)f2bf(a2 * inv) | ((unsigned)f2bf(a3 * inv) << 16);
            Mw[(size_t)row * 16 + c] = p;   // 16 lanes x 8B = 128B coalesced
        }
    }
}

// ---------------------------------------------------------------- MFMA GEMM
// H[N,64] = Am @ Wl^T + As @ Wr^T + bias (bf16 in, fp32 acc, bf16 out).
// Grid 782 blocks = 3128 waves = exactly 2 tiles/wave (no tail imbalance).
__global__ void gemm_kernel(const unsigned short* __restrict__ Am,
                            const unsigned short* __restrict__ As,
                            const float* __restrict__ Wl,
                            const float* __restrict__ Wr,
                            const float* __restrict__ bias,
                            unsigned short* __restrict__ H,
                            int relu) {
    int lane = threadIdx.x & 63;
    int m = lane & 15, quad = lane >> 4;

    bf16x8 wf[2][2][4];   // [matrix][kstep][ctile]
    for (int mat = 0; mat < 2; ++mat) {
        const float* W = mat ? Wr : Wl;
        for (int ks = 0; ks < 2; ++ks)
            for (int ct = 0; ct < 4; ++ct) {
                const float* p = W + (ct * 16 + m) * HID + ks * 32 + quad * 8;
                bf16x8 f;
                #pragma unroll
                for (int j = 0; j < 8; ++j) f[j] = (short)f2bf(p[j]);
                wf[mat][ks][ct] = f;
            }
    }
    float bv[4];
    #pragma unroll
    for (int ct = 0; ct < 4; ++ct) bv[ct] = bias[ct * 16 + m];

    int wpb = blockDim.x >> 6;
    int wid = blockIdx.x * wpb + (threadIdx.x >> 6);
    int stride = gridDim.x * wpb;
    const int NT = N_NODES / 16;
    for (int t = wid; t < NT; t += stride) {
        f32x4 acc[4] = {{0,0,0,0},{0,0,0,0},{0,0,0,0},{0,0,0,0}};
        size_t rowbase = ((size_t)t * 16 + m) * HID;
        #pragma unroll
        for (int ks = 0; ks < 2; ++ks) {
            bf16x8 a0 = *(const bf16x8*)(Am + rowbase + ks * 32 + quad * 8);
            bf16x8 a1 = *(const bf16x8*)(As + rowbase + ks * 32 + quad * 8);
            #pragma unroll
            for (int ct = 0; ct < 4; ++ct) {
                acc[ct] = __builtin_amdgcn_mfma_f32_16x16x32_bf16(a0, wf[0][ks][ct], acc[ct], 0, 0, 0);
                acc[ct] = __builtin_amdgcn_mfma_f32_16x16x32_bf16(a1, wf[1][ks][ct], acc[ct], 0, 0, 0);
            }
        }
        #pragma unroll
        for (int ct = 0; ct < 4; ++ct) {
            #pragma unroll
            for (int r = 0; r < 4; ++r) {
                float v = acc[ct][r] + bv[ct];
                if (relu) v = fmaxf(v, 0.f);
                H[((size_t)t * 16 + quad * 4 + r) * HID + ct * 16 + m] = f2bf(v);
            }
        }
    }
}

// ---------------------------------------------------------------- edge dot (bf16)
// 8 lanes per 2 consecutive edges: 4 uint4 loads/lane in flight,
// coalesced float2 output write. (At the ~3.7 TB/s L2-miss-path ceiling.)
__global__ void edge_dot_kernel(const int* __restrict__ src,
                                const int* __restrict__ dst,
                                const unsigned short* __restrict__ h,
                                float* __restrict__ out) {
    int t = blockIdx.x * blockDim.x + threadIdx.x;
    int g = t >> 3;                 // edge-pair group
    int c = t & 7;
    int e0 = g * 2;
    if (e0 >= N_EDGES) return;
    int a0 = src[e0],     b0 = dst[e0];
    int a1 = src[e0 + 1], b1 = dst[e0 + 1];
    const uint4* h4 = reinterpret_cast<const uint4*>(h);
    uint4 va0 = h4[(size_t)a0 * 8 + c];
    uint4 vb0 = h4[(size_t)b0 * 8 + c];
    uint4 va1 = h4[(size_t)a1 * 8 + c];
    uint4 vb1 = h4[(size_t)b1 * 8 + c];
    float p0 = bflo(va0.x) * bflo(vb0.x) + bfhi(va0.x) * bfhi(vb0.x)
             + bflo(va0.y) * bflo(vb0.y) + bfhi(va0.y) * bfhi(vb0.y)
             + bflo(va0.z) * bflo(vb0.z) + bfhi(va0.z) * bfhi(vb0.z)
             + bflo(va0.w) * bflo(vb0.w) + bfhi(va0.w) * bfhi(vb0.w);
    float p1 = bflo(va1.x) * bflo(vb1.x) + bfhi(va1.x) * bfhi(vb1.x)
             + bflo(va1.y) * bflo(vb1.y) + bfhi(va1.y) * bfhi(vb1.y)
             + bflo(va1.z) * bflo(vb1.z) + bfhi(va1.z) * bfhi(vb1.z)
             + bflo(va1.w) * bflo(vb1.w) + bfhi(va1.w) * bfhi(vb1.w);
    p0 += __shfl_xor(p0, 1); p0 += __shfl_xor(p0, 2); p0 += __shfl_xor(p0, 4);
    p1 += __shfl_xor(p1, 1); p1 += __shfl_xor(p1, 2); p1 += __shfl_xor(p1, 4);
    if (c == 0) reinterpret_cast<float2*>(out)[g] = make_float2(p0, p1);
}

extern "C" void kernel_launch(void* const* d_in, const int* in_sizes, int n_in,
                              void* d_out, int out_size, void* d_ws, size_t ws_size,
                              hipStream_t stream) {
    const float* emb = (const float*)d_in[0];
    const float* Wl1 = (const float*)d_in[1];
    const float* Wr1 = (const float*)d_in[2];
    const float* b1  = (const float*)d_in[3];
    const float* Wl2 = (const float*)d_in[4];
    const float* Wr2 = (const float*)d_in[5];
    const float* b2  = (const float*)d_in[6];
    const int*   nid = (const int*)d_in[7];
    const int*   ei  = (const int*)d_in[8];
    const int* esrc = ei;
    const int* edst = ei + N_EDGES;
    float* out = (float*)d_out;

    const size_t NH = (size_t)N_NODES * HID;   // 6.4M elements
    unsigned short* xh  = (unsigned short*)d_ws;          // [N,64] bf16
    unsigned short* h1h = xh + NH;                        // [N,64] bf16
    unsigned short* h2h = h1h + NH;                       // [N,64] bf16
    unsigned short* M   = h2h + NH;                       // [N,64] bf16 (mean agg)
    int* ib        = (int*)(M + NH);                      // int region
    int* row_start = ib;                          // [N+1]
    int* adj       = ib + N_NODES + 64;           // [E]
    int* pairs     = adj + N_EDGES + 64;          // [E] packed (src<<8 | dst&255)
    int* bhist     = pairs + N_EDGES + 64;        // [NB]
    int* boff      = bhist + NB + 1;              // [NB]
    int* bcursor   = boff + NB + 1;               // [NB]

    hipMemsetAsync(bhist, 0, NB * sizeof(int), stream);

    // xh = bf16(emb[node_id])  +  bucket histogram (role-split grid)
    gather_hist_kernel<<<G_GATHER + 256, 256, 0, stream>>>(emb, nid, xh, edst, bhist);

    // ---- CSR build via bucket counting sort (shared by both layers)
    bucket_scan<<<1, 512, 0, stream>>>(bhist, boff, bcursor);
    bucket_scatter<<<N_EDGES / C_EPB, 256, 0, stream>>>(esrc, edst, bcursor, pairs);
    bucket_csr<<<NB, 256, 0, stream>>>(pairs, boff, bcursor, row_start, adj);

    // ---- layer 1: aggregate then MFMA GEMM (+relu)
    agg_kernel<<<2048, 256, 0, stream>>>(row_start, adj, xh, M);
    gemm_kernel<<<782, 256, 0, stream>>>(M, xh, Wl1, Wr1, b1, h1h, 1);

    // ---- layer 2
    agg_kernel<<<2048, 256, 0, stream>>>(row_start, adj, h1h, M);
    gemm_kernel<<<782, 256, 0, stream>>>(M, h1h, Wl2, Wr2, b2, h2h, 0);

    // ---- edge classifier on bf16 features
    edge_dot_kernel<<<((size_t)(N_EDGES / 2) * 8 + 255) / 256, 256, 0, stream>>>(esrc, edst, h2h, out);
}